// Round 6
// baseline (329.737 us; speedup 1.0000x reference)
//
#include <hip/hip_runtime.h>
#include <math.h>

#define NFEAT 128
#define EPSBN 1e-5f
#define LDA 136   // bf16 elems per LDS row: 128 + 8 pad (272 B, 16B-aligned)

typedef __attribute__((ext_vector_type(8))) short short8;
typedef __attribute__((ext_vector_type(4))) float f32x4;

__device__ __forceinline__ unsigned short f2bf(float x) {
  union { float f; unsigned u; } v; v.f = x;
  unsigned r = v.u + 0x7FFF + ((v.u >> 16) & 1);   // RNE
  return (unsigned short)(r >> 16);
}
__device__ __forceinline__ float bf2f(unsigned short h) {
  union { unsigned u; float f; } v; v.u = (unsigned)h << 16;
  return v.f;
}

// ---------------------------------------------------------------------------
// K0: split Ws/Wi/Wr into bf16 hi/lo planes, stored in MFMA B-fragment order:
//   Whi[((m*4+kf)*4+kg)*1024 + c*8 + j] = bf16( W_m[(kf*32+kg*8+j)*128 + c] )
// ---------------------------------------------------------------------------
__global__ __launch_bounds__(256) void k0_wsplit(
    const float* __restrict__ Ws, const float* __restrict__ Wi,
    const float* __restrict__ Wr,
    short* __restrict__ Whi, short* __restrict__ Wlo)
{
  int t = blockIdx.x * 256 + threadIdx.x;   // 6144 total
  if (t >= 6144) return;
  int m   = t >> 11;
  int rem = t & 2047;
  int kf  = rem >> 9;
  int kg  = (rem >> 7) & 3;
  int c   = rem & 127;
  const float* W = (m == 0) ? Ws : ((m == 1) ? Wi : Wr);
  short hb[8], lb[8];
#pragma unroll
  for (int j = 0; j < 8; j++) {
    float w = W[(size_t)(kf * 32 + kg * 8 + j) * NFEAT + c];
    unsigned short h = f2bf(w);
    hb[j] = (short)h;
    lb[j] = (short)f2bf(w - bf2f(h));
  }
  int base = ((m * 16 + kf * 4 + kg) << 10) + (c << 3);
  *(short8*)&Whi[base] = *(short8*)hb;
  *(short8*)&Wlo[base] = *(short8*)lb;
}

// ---------------------------------------------------------------------------
// K1 (MFMA, split-bf16, cross-tile prefetch):
//   P_w = feature @ W_w + b_w + feature  for w in {s,i,r} + column stats.
// Grid-stride over 64-row tiles; 512 thr = 8 waves, wave wv owns 16 cols.
// Tile t+1's feat loads are issued before tile t's MFMA loop (latency hidden).
// ---------------------------------------------------------------------------
__global__ __launch_bounds__(512, 4) void k1_gemm(
    const float* __restrict__ feat,
    const short* __restrict__ Whi, const short* __restrict__ Wlo,
    const float* __restrict__ bs, const float* __restrict__ bi,
    const float* __restrict__ br,
    float* __restrict__ Pout,    // 3 consecutive N x 128 matrices
    float* __restrict__ stats,   // 6*128
    int N, int ntiles)
{
  __shared__ short Ah[64 * LDA];
  __shared__ short Al[64 * LDA];

  const int tid  = threadIdx.x;
  const int lane = tid & 63;
  const int wv   = tid >> 6;
  const int colb = wv * 16 + (lane & 15);
  const int kg   = lane >> 4;         // 0..3
  const int krow = kg * 8;

  const int sr = tid >> 3;            // staging row 0..63
  const int so = tid & 7;             // staging 16-float chunk

  const float bias[3] = {bs[colb], bi[colb], br[colb]};
  float ssum[3] = {0.f, 0.f, 0.f}, ssq[3] = {0.f, 0.f, 0.f};
  const size_t nf = (size_t)N * NFEAT;

  float4 pf[4];
  // prologue prefetch for first tile
  {
    int gr = blockIdx.x * 64 + sr; if (gr >= N) gr = N - 1;
    const float4* s4 = (const float4*)(feat + (size_t)gr * NFEAT + so * 16);
#pragma unroll
    for (int q = 0; q < 4; q++) pf[q] = s4[q];
  }

  for (int tile = blockIdx.x; tile < ntiles; tile += gridDim.x) {
    const int row0 = tile * 64;
    __syncthreads();                  // prior epilogue LDS readers done
    // ---- convert prefetched regs, write LDS hi/lo planes
    {
      short hbuf[16], lbuf[16];
#pragma unroll
      for (int q = 0; q < 4; q++) {
        float xs[4] = {pf[q].x, pf[q].y, pf[q].z, pf[q].w};
#pragma unroll
        for (int cc = 0; cc < 4; cc++) {
          unsigned short h = f2bf(xs[cc]);
          hbuf[q * 4 + cc] = (short)h;
          lbuf[q * 4 + cc] = (short)f2bf(xs[cc] - bf2f(h));
        }
      }
      short* dh = &Ah[sr * LDA + so * 16];
      short* dl = &Al[sr * LDA + so * 16];
      *(short8*)(dh)     = *(short8*)(hbuf);
      *(short8*)(dh + 8) = *(short8*)(hbuf + 8);
      *(short8*)(dl)     = *(short8*)(lbuf);
      *(short8*)(dl + 8) = *(short8*)(lbuf + 8);
    }
    __syncthreads();

    // ---- issue next tile's prefetch (consumed next iteration)
    {
      int ntile = tile + gridDim.x;
      if (ntile < ntiles) {
        int gr = ntile * 64 + sr; if (gr >= N) gr = N - 1;
        const float4* s4 = (const float4*)(feat + (size_t)gr * NFEAT + so * 16);
#pragma unroll
        for (int q = 0; q < 4; q++) pf[q] = s4[q];
      }
    }

    // ---- MFMA main loop
    f32x4 acc[3][4];
#pragma unroll
    for (int m = 0; m < 3; m++)
#pragma unroll
      for (int rf = 0; rf < 4; rf++)
        acc[m][rf] = (f32x4){0.f, 0.f, 0.f, 0.f};

#pragma unroll
    for (int kf = 0; kf < 4; kf++) {
      // B fragments for this kf (6 coalesced 16B loads, L2-hot)
      short8 bh[3], bl[3];
#pragma unroll
      for (int m = 0; m < 3; m++) {
        int fb = ((m * 16 + kf * 4 + kg) << 10) + (colb << 3);
        bh[m] = *(const short8*)&Whi[fb];
        bl[m] = *(const short8*)&Wlo[fb];
      }
      short8 ah[4], al[4];
#pragma unroll
      for (int rf = 0; rf < 4; rf++) {
        int off = (rf * 16 + (lane & 15)) * LDA + kf * 32 + krow;
        ah[rf] = *(const short8*)&Ah[off];
        al[rf] = *(const short8*)&Al[off];
      }
#pragma unroll
      for (int m = 0; m < 3; m++) {
#pragma unroll
        for (int rf = 0; rf < 4; rf++) {
          acc[m][rf] = __builtin_amdgcn_mfma_f32_16x16x32_bf16(
              ah[rf], bh[m], acc[m][rf], 0, 0, 0);
          acc[m][rf] = __builtin_amdgcn_mfma_f32_16x16x32_bf16(
              al[rf], bh[m], acc[m][rf], 0, 0, 0);
          acc[m][rf] = __builtin_amdgcn_mfma_f32_16x16x32_bf16(
              ah[rf], bl[m], acc[m][rf], 0, 0, 0);
        }
      }
    }

    // ---- epilogue: + bias + residual(from LDS), store P, accumulate stats
#pragma unroll
    for (int rf = 0; rf < 4; rf++) {
      int lrb = rf * 16 + kg * 4;
#pragma unroll
      for (int g = 0; g < 4; g++) {
        int lr = lrb + g;
        int gr = row0 + lr;
        bool ok = gr < N;
        float res = bf2f((unsigned short)Ah[lr * LDA + colb]) +
                    bf2f((unsigned short)Al[lr * LDA + colb]);
#pragma unroll
        for (int m = 0; m < 3; m++) {
          float v = acc[m][rf][g] + bias[m] + res;
          if (ok) {
            Pout[(size_t)m * nf + (size_t)gr * NFEAT + colb] = v;
            ssum[m] += v;
            ssq[m]  += v * v;
          }
        }
      }
    }
  }

  // ---- one atomic set per block
#pragma unroll
  for (int m = 0; m < 3; m++) {
    float s = ssum[m], q = ssq[m];
    s += __shfl_xor(s, 16); s += __shfl_xor(s, 32);
    q += __shfl_xor(q, 16); q += __shfl_xor(q, 32);
    if (kg == 0) {
      unsafeAtomicAdd(&stats[m * 256 + colb], s);
      unsafeAtomicAdd(&stats[m * 256 + 128 + colb], q);
    }
  }
}

// ---------------------------------------------------------------------------
// K2a (no stats dependency): fold back-half into MT (4 x 128 x 3) + cb.
//   logits = S@M1 + I@M3 + R@M4 + NB@M2 + cb
// MT layout: MT[cl*512 + part*128 + k], part: 0=S 1=I 2=R 3=NB.  grid=6.
// ---------------------------------------------------------------------------
__global__ void k2a_fold(
    const float* __restrict__ WtoI, const float* __restrict__ btoI,
    const float* __restrict__ WtoR, const float* __restrict__ btoR,
    const float* __restrict__ Wout, const float* __restrict__ bout,
    float* __restrict__ MT,   // 3*512
    float* __restrict__ cb)   // 4
{
  const int tid = threadIdx.x;
  int t = blockIdx.x * 256 + tid;     // 0..1535
  int cl = t / 512;
  int idx = t - cl * 512;
  int part = idx >> 7, k = idx & 127;
  float val;
  if (part == 0) {            // S: Wo1 + WtoI_top @ (Wo2-Wo1)
    float s = Wout[k * 3 + cl];
    for (int f = 0; f < 128; f++)
      s = fmaf(WtoI[k * 128 + f],
               Wout[(128 + f) * 3 + cl] - Wout[f * 3 + cl], s);
    val = s;
  } else if (part == 1) {     // I: Wo2 + WtoR @ (Wo3-Wo2)
    float s = Wout[(128 + k) * 3 + cl];
    for (int f = 0; f < 128; f++)
      s = fmaf(WtoR[k * 128 + f],
               Wout[(256 + f) * 3 + cl] - Wout[(128 + f) * 3 + cl], s);
    val = s;
  } else if (part == 2) {     // R: Wo3
    val = Wout[(256 + k) * 3 + cl];
  } else {                    // NB: WtoI_bot @ (Wo2-Wo1)
    float s = 0.f;
    for (int f = 0; f < 128; f++)
      s = fmaf(WtoI[(128 + k) * 128 + f],
               Wout[(128 + f) * 3 + cl] - Wout[f * 3 + cl], s);
    val = s;
  }
  MT[cl * 512 + idx] = val;

  if (blockIdx.x == 0 && tid < 3) {
    float s = bout[tid];
    for (int f = 0; f < 128; f++) {
      s = fmaf(btoI[f], Wout[(128 + f) * 3 + tid] - Wout[f * 3 + tid], s);
      s = fmaf(btoR[f], Wout[(256 + f) * 3 + tid] - Wout[(128 + f) * 3 + tid], s);
    }
    cb[tid] = s;
  }
}

// ---------------------------------------------------------------------------
// K2b: BN scale/shift from stats (1 block).
// ---------------------------------------------------------------------------
__global__ void k2b_bn(
    const float* __restrict__ stats,
    const float* __restrict__ gamma, const float* __restrict__ beta,
    float* __restrict__ bn,   // 6*128: [w]{a[128], b[128]}
    int N)
{
  const int tid = threadIdx.x;
  const float invN = 1.0f / (float)N;
  for (int t = tid; t < 384; t += 256) {
    int w = t >> 7, c = t & 127;
    float sm = stats[w * 256 + c];
    float sq = stats[w * 256 + 128 + c];
    float m = sm * invN;
    float v = sq * invN - m * m;
    float rinv = rsqrtf(v + EPSBN);
    float a = gamma[c] * rinv;
    bn[w * 256 + c] = a;
    bn[w * 256 + 128 + c] = beta[c] - m * a;
  }
}

// ---------------------------------------------------------------------------
// K_edge3: per edge, logit3[dst] += w * (relu(bn_i(Pi[src])) @ M2).
// 32 lanes/edge (coalesced 512B row read), shfl-reduce, 3 atomics/edge.
// ---------------------------------------------------------------------------
__global__ __launch_bounds__(256) void k_edge3(
    const float* __restrict__ Pi,
    const int* __restrict__ eidx, const float* __restrict__ ew,
    const float* __restrict__ bn, const float* __restrict__ MT,
    float* __restrict__ logit3, int E)
{
  long gid = (long)blockIdx.x * 256 + threadIdx.x;
  int e = (int)(gid >> 5);
  if (e >= E) return;
  const int c = (threadIdx.x & 31) * 4;

  int src = eidx[e];
  int dst = eidx[E + e];
  float w = ew[e];

  float4 x = *(const float4*)&Pi[(size_t)src * NFEAT + c];
  float4 a = *(const float4*)&bn[256 + c];
  float4 b = *(const float4*)&bn[256 + 128 + c];
  float m0 = fmaxf(fmaf(a.x, x.x, b.x), 0.f);
  float m1 = fmaxf(fmaf(a.y, x.y, b.y), 0.f);
  float m2 = fmaxf(fmaf(a.z, x.z, b.z), 0.f);
  float m3 = fmaxf(fmaf(a.w, x.w, b.w), 0.f);

  float l[3];
#pragma unroll
  for (int cl = 0; cl < 3; cl++) {
    float4 m = *(const float4*)&MT[cl * 512 + 384 + c];
    l[cl] = m0 * m.x + m1 * m.y + m2 * m.z + m3 * m.w;
  }
#pragma unroll
  for (int off = 1; off < 32; off <<= 1) {
    l[0] += __shfl_xor(l[0], off);
    l[1] += __shfl_xor(l[1], off);
    l[2] += __shfl_xor(l[2], off);
  }
  if ((threadIdx.x & 31) == 0) {
    float* o = &logit3[(size_t)dst * 4];
    unsafeAtomicAdd(o + 0, l[0] * w);
    unsafeAtomicAdd(o + 1, l[1] * w);
    unsafeAtomicAdd(o + 2, l[2] * w);
  }
}

// ---------------------------------------------------------------------------
// K4: per-row fused BN+ReLU, S/I/R dots with folded MT + neighbor logits,
// softmax.  16 lanes/row.
// ---------------------------------------------------------------------------
__global__ __launch_bounds__(256) void k4_final(
    const float* __restrict__ P,   // 3 consecutive N x 128
    const float* __restrict__ logit3,
    const float* __restrict__ bn,
    const float* __restrict__ MT,
    const float* __restrict__ cb,
    float* __restrict__ out, int N)
{
  __shared__ float MTs[1536];
  __shared__ float bns[768];
  const int tid = threadIdx.x;
  for (int i = tid; i < 1536; i += 256) MTs[i] = MT[i];
  for (int i = tid; i < 768; i += 256) bns[i] = bn[i];
  __syncthreads();

  const int row0 = blockIdx.x * 16 + (tid >> 4);
  const int row  = (row0 < N) ? row0 : (N - 1);
  const int p   = tid & 15;
  const int mp  = p >> 2;       // 0=S 1=I 2=R 3=logit3
  const int seg = p & 3;

  float pa0 = 0.f, pa1 = 0.f, pa2 = 0.f;
  if (mp < 3) {
    const float* xsrc = P + ((size_t)mp * N + row) * NFEAT + seg * 32;
#pragma unroll
    for (int i = 0; i < 8; i++) {
      float4 x = *(const float4*)&xsrc[i * 4];
      int c = seg * 32 + i * 4;
      float4 a = *(float4*)&bns[mp * 256 + c];
      float4 b = *(float4*)&bns[mp * 256 + 128 + c];
      x.x = fmaxf(fmaf(a.x, x.x, b.x), 0.f);
      x.y = fmaxf(fmaf(a.y, x.y, b.y), 0.f);
      x.z = fmaxf(fmaf(a.z, x.z, b.z), 0.f);
      x.w = fmaxf(fmaf(a.w, x.w, b.w), 0.f);
      int mo = mp * 128 + c;
      {
        float4 m = *(float4*)&MTs[0 * 512 + mo];
        pa0 += x.x * m.x + x.y * m.y + x.z * m.z + x.w * m.w;
      }
      {
        float4 m = *(float4*)&MTs[1 * 512 + mo];
        pa1 += x.x * m.x + x.y * m.y + x.z * m.z + x.w * m.w;
      }
      {
        float4 m = *(float4*)&MTs[2 * 512 + mo];
        pa2 += x.x * m.x + x.y * m.y + x.z * m.z + x.w * m.w;
      }
    }
  } else if (seg == 0) {
    float4 L = *(const float4*)&logit3[(size_t)row * 4];
    pa0 = L.x; pa1 = L.y; pa2 = L.z;
  }

#pragma unroll
  for (int off = 1; off < 16; off <<= 1) {
    pa0 += __shfl_xor(pa0, off);
    pa1 += __shfl_xor(pa1, off);
    pa2 += __shfl_xor(pa2, off);
  }
  if (p == 0 && row0 < N) {
    float l0 = pa0 + cb[0], l1 = pa1 + cb[1], l2 = pa2 + cb[2];
    float mx = fmaxf(l0, fmaxf(l1, l2));
    float e0 = expf(l0 - mx), e1 = expf(l1 - mx), e2 = expf(l2 - mx);
    float inv = 1.f / (e0 + e1 + e2);
    out[(size_t)row0 * 3 + 0] = e0 * inv;
    out[(size_t)row0 * 3 + 1] = e1 * inv;
    out[(size_t)row0 * 3 + 2] = e2 * inv;
  }
}

// ---------------------------------------------------------------------------
extern "C" void kernel_launch(void* const* d_in, const int* in_sizes, int n_in,
                              void* d_out, int out_size, void* d_ws, size_t ws_size,
                              hipStream_t stream)
{
  const float* feat  = (const float*)d_in[0];
  const int*   eidx  = (const int*)  d_in[1];
  const float* ew    = (const float*)d_in[2];
  const float* Ws    = (const float*)d_in[3];
  const float* bs    = (const float*)d_in[4];
  const float* Wi    = (const float*)d_in[5];
  const float* bi    = (const float*)d_in[6];
  const float* Wr    = (const float*)d_in[7];
  const float* br    = (const float*)d_in[8];
  const float* gamma = (const float*)d_in[9];
  const float* beta  = (const float*)d_in[10];
  const float* WtoI  = (const float*)d_in[11];
  const float* btoI  = (const float*)d_in[12];
  const float* WtoR  = (const float*)d_in[13];
  const float* btoR  = (const float*)d_in[14];
  const float* Wout  = (const float*)d_in[15];
  const float* bout  = (const float*)d_in[16];

  const int N = in_sizes[0] / NFEAT;
  const int E = in_sizes[2];
  float* out = (float*)d_out;

  const size_t nf = (size_t)N * NFEAT;
  float* P      = (float*)d_ws;           // 3*nf
  float* logit3 = P + 3 * nf;             // 4*N
  float* stats  = logit3 + 4 * (size_t)N; // 768
  float* bn     = stats + 768;            // 768
  float* MT     = bn + 768;               // 1536
  float* cb     = MT + 1536;              // 4
  short* Whi    = (short*)(cb + 4);       // 49152
  short* Wlo    = Whi + 49152;            // 49152

  hipMemsetAsync(stats, 0, 768 * sizeof(float), stream);
  hipMemsetAsync(logit3, 0, 4 * (size_t)N * sizeof(float), stream);

  const int nt = (N + 63) / 64;           // 1563
  const int g1 = (nt + 2) / 3;            // 521: 3 tiles per block

  k0_wsplit<<<24, 256, 0, stream>>>(Ws, Wi, Wr, Whi, Wlo);
  k2a_fold<<<6, 256, 0, stream>>>(WtoI, btoI, WtoR, btoR, Wout, bout, MT, cb);
  k1_gemm<<<g1, 512, 0, stream>>>(feat, Whi, Wlo, bs, bi, br, P, stats, N, nt);
  k2b_bn<<<1, 256, 0, stream>>>(stats, gamma, beta, bn, N);

  const long nth = (long)E * 32;
  k_edge3<<<(int)((nth + 255) / 256), 256, 0, stream>>>(P + nf, eidx, ew, bn,
                                                        MT, logit3, E);
  k4_final<<<(N + 15) / 16, 256, 0, stream>>>(P, logit3, bn, MT, cb, out, N);
}

// Round 7
// 248.342 us; speedup vs baseline: 1.3278x; 1.3278x over previous
//
#include <hip/hip_runtime.h>
#include <math.h>

#define NFEAT 128
#define EPSBN 1e-5f
#define LDA 136   // bf16 elems per LDS row: 128 + 8 pad (272 B, 16B-aligned)

typedef __attribute__((ext_vector_type(8))) short short8;
typedef __attribute__((ext_vector_type(4))) float f32x4;

__device__ __forceinline__ unsigned short f2bf(float x) {
  union { float f; unsigned u; } v; v.f = x;
  unsigned r = v.u + 0x7FFF + ((v.u >> 16) & 1);   // RNE
  return (unsigned short)(r >> 16);
}
__device__ __forceinline__ float bf2f(unsigned short h) {
  union { unsigned u; float f; } v; v.u = (unsigned)h << 16;
  return v.f;
}

// ---------------------------------------------------------------------------
// K0: split Ws/Wi/Wr into bf16 hi/lo planes, stored in MFMA B-fragment order:
//   Whi[((m*4+kf)*4+kg)*1024 + c*8 + j] = bf16( W_m[(kf*32+kg*8+j)*128 + c] )
// ---------------------------------------------------------------------------
__global__ __launch_bounds__(256) void k0_wsplit(
    const float* __restrict__ Ws, const float* __restrict__ Wi,
    const float* __restrict__ Wr,
    short* __restrict__ Whi, short* __restrict__ Wlo)
{
  int t = blockIdx.x * 256 + threadIdx.x;   // 6144 total
  if (t >= 6144) return;
  int m   = t >> 11;
  int rem = t & 2047;
  int kf  = rem >> 9;
  int kg  = (rem >> 7) & 3;
  int c   = rem & 127;
  const float* W = (m == 0) ? Ws : ((m == 1) ? Wi : Wr);
  short hb[8], lb[8];
#pragma unroll
  for (int j = 0; j < 8; j++) {
    float w = W[(size_t)(kf * 32 + kg * 8 + j) * NFEAT + c];
    unsigned short h = f2bf(w);
    hb[j] = (short)h;
    lb[j] = (short)f2bf(w - bf2f(h));
  }
  int base = ((m * 16 + kf * 4 + kg) << 10) + (c << 3);
  *(short8*)&Whi[base] = *(short8*)hb;
  *(short8*)&Wlo[base] = *(short8*)lb;
}

// ---------------------------------------------------------------------------
// K1 (MFMA, split-bf16, cross-tile prefetch):
//   P_w = feature @ W_w + b_w + feature  for w in {s,i,r} + column stats.
// Grid-stride over 64-row tiles; 512 thr = 8 waves, wave wv owns 16 cols.
// launch_bounds(512,2): VGPR cap 256 — (512,4) forced 64 VGPR and spilled
// ~210 MB/dispatch to scratch (R6 regression).
// ---------------------------------------------------------------------------
__global__ __launch_bounds__(512, 2) void k1_gemm(
    const float* __restrict__ feat,
    const short* __restrict__ Whi, const short* __restrict__ Wlo,
    const float* __restrict__ bs, const float* __restrict__ bi,
    const float* __restrict__ br,
    float* __restrict__ Pout,    // 3 consecutive N x 128 matrices
    float* __restrict__ stats,   // 6*128
    int N, int ntiles)
{
  __shared__ short Ah[64 * LDA];
  __shared__ short Al[64 * LDA];

  const int tid  = threadIdx.x;
  const int lane = tid & 63;
  const int wv   = tid >> 6;
  const int colb = wv * 16 + (lane & 15);
  const int kg   = lane >> 4;         // 0..3
  const int krow = kg * 8;

  const int sr = tid >> 3;            // staging row 0..63
  const int so = tid & 7;             // staging 16-float chunk

  const float bias[3] = {bs[colb], bi[colb], br[colb]};
  float ssum[3] = {0.f, 0.f, 0.f}, ssq[3] = {0.f, 0.f, 0.f};
  const size_t nf = (size_t)N * NFEAT;

  float4 pf[4];
  // prologue prefetch for first tile
  {
    int gr = blockIdx.x * 64 + sr; if (gr >= N) gr = N - 1;
    const float4* s4 = (const float4*)(feat + (size_t)gr * NFEAT + so * 16);
#pragma unroll
    for (int q = 0; q < 4; q++) pf[q] = s4[q];
  }

  for (int tile = blockIdx.x; tile < ntiles; tile += gridDim.x) {
    const int row0 = tile * 64;
    __syncthreads();                  // prior epilogue LDS readers done
    // ---- convert prefetched regs, write LDS hi/lo planes
    {
      short hbuf[16], lbuf[16];
#pragma unroll
      for (int q = 0; q < 4; q++) {
        float xs[4] = {pf[q].x, pf[q].y, pf[q].z, pf[q].w};
#pragma unroll
        for (int cc = 0; cc < 4; cc++) {
          unsigned short h = f2bf(xs[cc]);
          hbuf[q * 4 + cc] = (short)h;
          lbuf[q * 4 + cc] = (short)f2bf(xs[cc] - bf2f(h));
        }
      }
      short* dh = &Ah[sr * LDA + so * 16];
      short* dl = &Al[sr * LDA + so * 16];
      *(short8*)(dh)     = *(short8*)(hbuf);
      *(short8*)(dh + 8) = *(short8*)(hbuf + 8);
      *(short8*)(dl)     = *(short8*)(lbuf);
      *(short8*)(dl + 8) = *(short8*)(lbuf + 8);
    }
    __syncthreads();

    // ---- issue next tile's prefetch (consumed next iteration)
    {
      int ntile = tile + gridDim.x;
      if (ntile < ntiles) {
        int gr = ntile * 64 + sr; if (gr >= N) gr = N - 1;
        const float4* s4 = (const float4*)(feat + (size_t)gr * NFEAT + so * 16);
#pragma unroll
        for (int q = 0; q < 4; q++) pf[q] = s4[q];
      }
    }

    // ---- MFMA main loop
    f32x4 acc[3][4];
#pragma unroll
    for (int m = 0; m < 3; m++)
#pragma unroll
      for (int rf = 0; rf < 4; rf++)
        acc[m][rf] = (f32x4){0.f, 0.f, 0.f, 0.f};

#pragma unroll
    for (int kf = 0; kf < 4; kf++) {
      // B fragments for this kf (6 coalesced 16B loads, L2-hot)
      short8 bh[3], bl[3];
#pragma unroll
      for (int m = 0; m < 3; m++) {
        int fb = ((m * 16 + kf * 4 + kg) << 10) + (colb << 3);
        bh[m] = *(const short8*)&Whi[fb];
        bl[m] = *(const short8*)&Wlo[fb];
      }
      short8 ah[4], al[4];
#pragma unroll
      for (int rf = 0; rf < 4; rf++) {
        int off = (rf * 16 + (lane & 15)) * LDA + kf * 32 + krow;
        ah[rf] = *(const short8*)&Ah[off];
        al[rf] = *(const short8*)&Al[off];
      }
#pragma unroll
      for (int m = 0; m < 3; m++) {
#pragma unroll
        for (int rf = 0; rf < 4; rf++) {
          acc[m][rf] = __builtin_amdgcn_mfma_f32_16x16x32_bf16(
              ah[rf], bh[m], acc[m][rf], 0, 0, 0);
          acc[m][rf] = __builtin_amdgcn_mfma_f32_16x16x32_bf16(
              al[rf], bh[m], acc[m][rf], 0, 0, 0);
          acc[m][rf] = __builtin_amdgcn_mfma_f32_16x16x32_bf16(
              ah[rf], bl[m], acc[m][rf], 0, 0, 0);
        }
      }
    }

    // ---- epilogue: + bias + residual(from LDS), store P, accumulate stats
#pragma unroll
    for (int rf = 0; rf < 4; rf++) {
      int lrb = rf * 16 + kg * 4;
#pragma unroll
      for (int g = 0; g < 4; g++) {
        int lr = lrb + g;
        int gr = row0 + lr;
        bool ok = gr < N;
        float res = bf2f((unsigned short)Ah[lr * LDA + colb]) +
                    bf2f((unsigned short)Al[lr * LDA + colb]);
#pragma unroll
        for (int m = 0; m < 3; m++) {
          float v = acc[m][rf][g] + bias[m] + res;
          if (ok) {
            Pout[(size_t)m * nf + (size_t)gr * NFEAT + colb] = v;
            ssum[m] += v;
            ssq[m]  += v * v;
          }
        }
      }
    }
  }

  // ---- one atomic set per block
#pragma unroll
  for (int m = 0; m < 3; m++) {
    float s = ssum[m], q = ssq[m];
    s += __shfl_xor(s, 16); s += __shfl_xor(s, 32);
    q += __shfl_xor(q, 16); q += __shfl_xor(q, 32);
    if (kg == 0) {
      unsafeAtomicAdd(&stats[m * 256 + colb], s);
      unsafeAtomicAdd(&stats[m * 256 + 128 + colb], q);
    }
  }
}

// ---------------------------------------------------------------------------
// K2a (no stats dependency): fold back-half into MT (4 x 128 x 3) + cb.
//   logits = S@M1 + I@M3 + R@M4 + NB@M2 + cb
// MT layout: MT[cl*512 + part*128 + k], part: 0=S 1=I 2=R 3=NB.  grid=6.
// ---------------------------------------------------------------------------
__global__ void k2a_fold(
    const float* __restrict__ WtoI, const float* __restrict__ btoI,
    const float* __restrict__ WtoR, const float* __restrict__ btoR,
    const float* __restrict__ Wout, const float* __restrict__ bout,
    float* __restrict__ MT,   // 3*512
    float* __restrict__ cb)   // 4
{
  const int tid = threadIdx.x;
  int t = blockIdx.x * 256 + tid;     // 0..1535
  int cl = t / 512;
  int idx = t - cl * 512;
  int part = idx >> 7, k = idx & 127;
  float val;
  if (part == 0) {            // S: Wo1 + WtoI_top @ (Wo2-Wo1)
    float s = Wout[k * 3 + cl];
    for (int f = 0; f < 128; f++)
      s = fmaf(WtoI[k * 128 + f],
               Wout[(128 + f) * 3 + cl] - Wout[f * 3 + cl], s);
    val = s;
  } else if (part == 1) {     // I: Wo2 + WtoR @ (Wo3-Wo2)
    float s = Wout[(128 + k) * 3 + cl];
    for (int f = 0; f < 128; f++)
      s = fmaf(WtoR[k * 128 + f],
               Wout[(256 + f) * 3 + cl] - Wout[(128 + f) * 3 + cl], s);
    val = s;
  } else if (part == 2) {     // R: Wo3
    val = Wout[(256 + k) * 3 + cl];
  } else {                    // NB: WtoI_bot @ (Wo2-Wo1)
    float s = 0.f;
    for (int f = 0; f < 128; f++)
      s = fmaf(WtoI[(128 + k) * 128 + f],
               Wout[(128 + f) * 3 + cl] - Wout[f * 3 + cl], s);
    val = s;
  }
  MT[cl * 512 + idx] = val;

  if (blockIdx.x == 0 && tid < 3) {
    float s = bout[tid];
    for (int f = 0; f < 128; f++) {
      s = fmaf(btoI[f], Wout[(128 + f) * 3 + tid] - Wout[f * 3 + tid], s);
      s = fmaf(btoR[f], Wout[(256 + f) * 3 + tid] - Wout[(128 + f) * 3 + tid], s);
    }
    cb[tid] = s;
  }
}

// ---------------------------------------------------------------------------
// K2b: BN scale/shift from stats (1 block).
// ---------------------------------------------------------------------------
__global__ void k2b_bn(
    const float* __restrict__ stats,
    const float* __restrict__ gamma, const float* __restrict__ beta,
    float* __restrict__ bn,   // 6*128: [w]{a[128], b[128]}
    int N)
{
  const int tid = threadIdx.x;
  const float invN = 1.0f / (float)N;
  for (int t = tid; t < 384; t += 256) {
    int w = t >> 7, c = t & 127;
    float sm = stats[w * 256 + c];
    float sq = stats[w * 256 + 128 + c];
    float m = sm * invN;
    float v = sq * invN - m * m;
    float rinv = rsqrtf(v + EPSBN);
    float a = gamma[c] * rinv;
    bn[w * 256 + c] = a;
    bn[w * 256 + 128 + c] = beta[c] - m * a;
  }
}

// ---------------------------------------------------------------------------
// KQ: per-node projection  q[r] = relu(bn_i(P_i[r])) @ M2   (32 lanes/row).
// Hoists the @M2 out of the edge loop: NB[dst]@M2 == sum_e w_e * q[src_e].
// ---------------------------------------------------------------------------
__global__ __launch_bounds__(256) void kq_proj(
    const float* __restrict__ Pi,
    const float* __restrict__ bn, const float* __restrict__ MT,
    float* __restrict__ q, int N)
{
  int r = blockIdx.x * 8 + (threadIdx.x >> 5);
  if (r >= N) return;
  const int c = (threadIdx.x & 31) * 4;

  float4 x = *(const float4*)&Pi[(size_t)r * NFEAT + c];
  float4 a = *(const float4*)&bn[256 + c];
  float4 b = *(const float4*)&bn[256 + 128 + c];
  float m0 = fmaxf(fmaf(a.x, x.x, b.x), 0.f);
  float m1 = fmaxf(fmaf(a.y, x.y, b.y), 0.f);
  float m2 = fmaxf(fmaf(a.z, x.z, b.z), 0.f);
  float m3 = fmaxf(fmaf(a.w, x.w, b.w), 0.f);

  float l[3];
#pragma unroll
  for (int cl = 0; cl < 3; cl++) {
    float4 m = *(const float4*)&MT[cl * 512 + 384 + c];
    l[cl] = m0 * m.x + m1 * m.y + m2 * m.z + m3 * m.w;
  }
#pragma unroll
  for (int off = 1; off < 32; off <<= 1) {
    l[0] += __shfl_xor(l[0], off);
    l[1] += __shfl_xor(l[1], off);
    l[2] += __shfl_xor(l[2], off);
  }
  if ((threadIdx.x & 31) == 0)
    *(float4*)&q[(size_t)r * 4] = make_float4(l[0], l[1], l[2], 0.f);
}

// ---------------------------------------------------------------------------
// K_edge: 1 thread/edge.  logit3[dst] += w * q[src]   (3 atomics/edge,
// q is 1.6 MB -> L2-resident random reads).
// ---------------------------------------------------------------------------
__global__ __launch_bounds__(256) void k_edge(
    const int* __restrict__ eidx, const float* __restrict__ ew,
    const float* __restrict__ q, float* __restrict__ logit3, int E)
{
  int e = blockIdx.x * 256 + threadIdx.x;
  if (e >= E) return;
  int src = eidx[e];
  int dst = eidx[E + e];
  float w = ew[e];
  float4 qa = *(const float4*)&q[(size_t)src * 4];
  float* o = &logit3[(size_t)dst * 4];
  unsafeAtomicAdd(o + 0, qa.x * w);
  unsafeAtomicAdd(o + 1, qa.y * w);
  unsafeAtomicAdd(o + 2, qa.z * w);
}

// ---------------------------------------------------------------------------
// K4: per-row fused BN+ReLU, S/I/R dots with folded MT + neighbor logits,
// softmax.  16 lanes/row.
// ---------------------------------------------------------------------------
__global__ __launch_bounds__(256) void k4_final(
    const float* __restrict__ P,   // 3 consecutive N x 128
    const float* __restrict__ logit3,
    const float* __restrict__ bn,
    const float* __restrict__ MT,
    const float* __restrict__ cb,
    float* __restrict__ out, int N)
{
  __shared__ float MTs[1536];
  __shared__ float bns[768];
  const int tid = threadIdx.x;
  for (int i = tid; i < 1536; i += 256) MTs[i] = MT[i];
  for (int i = tid; i < 768; i += 256) bns[i] = bn[i];
  __syncthreads();

  const int row0 = blockIdx.x * 16 + (tid >> 4);
  const int row  = (row0 < N) ? row0 : (N - 1);
  const int p   = tid & 15;
  const int mp  = p >> 2;       // 0=S 1=I 2=R 3=logit3
  const int seg = p & 3;

  float pa0 = 0.f, pa1 = 0.f, pa2 = 0.f;
  if (mp < 3) {
    const float* xsrc = P + ((size_t)mp * N + row) * NFEAT + seg * 32;
#pragma unroll
    for (int i = 0; i < 8; i++) {
      float4 x = *(const float4*)&xsrc[i * 4];
      int c = seg * 32 + i * 4;
      float4 a = *(float4*)&bns[mp * 256 + c];
      float4 b = *(float4*)&bns[mp * 256 + 128 + c];
      x.x = fmaxf(fmaf(a.x, x.x, b.x), 0.f);
      x.y = fmaxf(fmaf(a.y, x.y, b.y), 0.f);
      x.z = fmaxf(fmaf(a.z, x.z, b.z), 0.f);
      x.w = fmaxf(fmaf(a.w, x.w, b.w), 0.f);
      int mo = mp * 128 + c;
      {
        float4 m = *(float4*)&MTs[0 * 512 + mo];
        pa0 += x.x * m.x + x.y * m.y + x.z * m.z + x.w * m.w;
      }
      {
        float4 m = *(float4*)&MTs[1 * 512 + mo];
        pa1 += x.x * m.x + x.y * m.y + x.z * m.z + x.w * m.w;
      }
      {
        float4 m = *(float4*)&MTs[2 * 512 + mo];
        pa2 += x.x * m.x + x.y * m.y + x.z * m.z + x.w * m.w;
      }
    }
  } else if (seg == 0) {
    float4 L = *(const float4*)&logit3[(size_t)row * 4];
    pa0 = L.x; pa1 = L.y; pa2 = L.z;
  }

#pragma unroll
  for (int off = 1; off < 16; off <<= 1) {
    pa0 += __shfl_xor(pa0, off);
    pa1 += __shfl_xor(pa1, off);
    pa2 += __shfl_xor(pa2, off);
  }
  if (p == 0 && row0 < N) {
    float l0 = pa0 + cb[0], l1 = pa1 + cb[1], l2 = pa2 + cb[2];
    float mx = fmaxf(l0, fmaxf(l1, l2));
    float e0 = expf(l0 - mx), e1 = expf(l1 - mx), e2 = expf(l2 - mx);
    float inv = 1.f / (e0 + e1 + e2);
    out[(size_t)row0 * 3 + 0] = e0 * inv;
    out[(size_t)row0 * 3 + 1] = e1 * inv;
    out[(size_t)row0 * 3 + 2] = e2 * inv;
  }
}

// ---------------------------------------------------------------------------
extern "C" void kernel_launch(void* const* d_in, const int* in_sizes, int n_in,
                              void* d_out, int out_size, void* d_ws, size_t ws_size,
                              hipStream_t stream)
{
  const float* feat  = (const float*)d_in[0];
  const int*   eidx  = (const int*)  d_in[1];
  const float* ew    = (const float*)d_in[2];
  const float* Ws    = (const float*)d_in[3];
  const float* bs    = (const float*)d_in[4];
  const float* Wi    = (const float*)d_in[5];
  const float* bi    = (const float*)d_in[6];
  const float* Wr    = (const float*)d_in[7];
  const float* br    = (const float*)d_in[8];
  const float* gamma = (const float*)d_in[9];
  const float* beta  = (const float*)d_in[10];
  const float* WtoI  = (const float*)d_in[11];
  const float* btoI  = (const float*)d_in[12];
  const float* WtoR  = (const float*)d_in[13];
  const float* btoR  = (const float*)d_in[14];
  const float* Wout  = (const float*)d_in[15];
  const float* bout  = (const float*)d_in[16];

  const int N = in_sizes[0] / NFEAT;
  const int E = in_sizes[2];
  float* out = (float*)d_out;

  const size_t nf = (size_t)N * NFEAT;
  float* P      = (float*)d_ws;           // 3*nf
  float* logit3 = P + 3 * nf;             // 4*N
  float* q      = logit3 + 4 * (size_t)N; // 4*N
  float* stats  = q + 4 * (size_t)N;      // 768
  float* bn     = stats + 768;            // 768
  float* MT     = bn + 768;               // 1536
  float* cb     = MT + 1536;              // 4
  short* Whi    = (short*)(cb + 4);       // 49152
  short* Wlo    = Whi + 49152;            // 49152

  hipMemsetAsync(stats, 0, 768 * sizeof(float), stream);
  hipMemsetAsync(logit3, 0, 4 * (size_t)N * sizeof(float), stream);

  const int nt = (N + 63) / 64;           // 1563
  const int g1 = (nt + 2) / 3;            // 521: 3 tiles per block

  k0_wsplit<<<24, 256, 0, stream>>>(Ws, Wi, Wr, Whi, Wlo);
  k2a_fold<<<6, 256, 0, stream>>>(WtoI, btoI, WtoR, btoR, Wout, bout, MT, cb);
  k1_gemm<<<g1, 512, 0, stream>>>(feat, Whi, Wlo, bs, bi, br, P, stats, N, nt);
  k2b_bn<<<1, 256, 0, stream>>>(stats, gamma, beta, bn, N);

  kq_proj<<<(N + 7) / 8, 256, 0, stream>>>(P + nf, bn, MT, q, N);
  k_edge<<<(E + 255) / 256, 256, 0, stream>>>(eidx, ew, q, logit3, E);
  k4_final<<<(N + 15) / 16, 256, 0, stream>>>(P, logit3, bn, MT, cb, out, N);
}

// Round 8
// 190.184 us; speedup vs baseline: 1.7338x; 1.3058x over previous
//
#include <hip/hip_runtime.h>
#include <math.h>

#define NFEAT 128
#define EPSBN 1e-5f
#define LDA 136   // bf16 elems per LDS row: 128 + 8 pad (272 B, 16B-aligned)
#define NREP 8    // logit3 replicas to spread atomic contention

typedef __attribute__((ext_vector_type(8))) short short8;
typedef __attribute__((ext_vector_type(4))) float f32x4;

__device__ __forceinline__ unsigned short f2bf(float x) {
  union { float f; unsigned u; } v; v.f = x;
  unsigned r = v.u + 0x7FFF + ((v.u >> 16) & 1);   // RNE
  return (unsigned short)(r >> 16);
}
__device__ __forceinline__ float bf2f(unsigned short h) {
  union { unsigned u; float f; } v; v.u = (unsigned)h << 16;
  return v.f;
}

// ---------------------------------------------------------------------------
// K0: split Ws/Wi/Wr into bf16 hi/lo planes, stored in MFMA B-fragment order.
// ---------------------------------------------------------------------------
__global__ __launch_bounds__(256) void k0_wsplit(
    const float* __restrict__ Ws, const float* __restrict__ Wi,
    const float* __restrict__ Wr,
    short* __restrict__ Whi, short* __restrict__ Wlo)
{
  int t = blockIdx.x * 256 + threadIdx.x;   // 6144 total
  if (t >= 6144) return;
  int m   = t >> 11;
  int rem = t & 2047;
  int kf  = rem >> 9;
  int kg  = (rem >> 7) & 3;
  int c   = rem & 127;
  const float* W = (m == 0) ? Ws : ((m == 1) ? Wi : Wr);
  short hb[8], lb[8];
#pragma unroll
  for (int j = 0; j < 8; j++) {
    float w = W[(size_t)(kf * 32 + kg * 8 + j) * NFEAT + c];
    unsigned short h = f2bf(w);
    hb[j] = (short)h;
    lb[j] = (short)f2bf(w - bf2f(h));
  }
  int base = ((m * 16 + kf * 4 + kg) << 10) + (c << 3);
  *(short8*)&Whi[base] = *(short8*)hb;
  *(short8*)&Wlo[base] = *(short8*)lb;
}

// ---------------------------------------------------------------------------
// K1 (MFMA, split-bf16, cross-tile prefetch):
//   P_w = feature @ W_w + b_w + feature  for w in {s,i,r} + column stats.
// launch_bounds(512,2): VGPR cap 256 — (512,4) forced 64 VGPR and spilled
// ~210 MB/dispatch to scratch (R6 regression).
// ---------------------------------------------------------------------------
__global__ __launch_bounds__(512, 2) void k1_gemm(
    const float* __restrict__ feat,
    const short* __restrict__ Whi, const short* __restrict__ Wlo,
    const float* __restrict__ bs, const float* __restrict__ bi,
    const float* __restrict__ br,
    float* __restrict__ Pout,    // 3 consecutive N x 128 matrices
    float* __restrict__ stats,   // 6*128
    int N, int ntiles)
{
  __shared__ short Ah[64 * LDA];
  __shared__ short Al[64 * LDA];

  const int tid  = threadIdx.x;
  const int lane = tid & 63;
  const int wv   = tid >> 6;
  const int colb = wv * 16 + (lane & 15);
  const int kg   = lane >> 4;         // 0..3
  const int krow = kg * 8;

  const int sr = tid >> 3;            // staging row 0..63
  const int so = tid & 7;             // staging 16-float chunk

  const float bias[3] = {bs[colb], bi[colb], br[colb]};
  float ssum[3] = {0.f, 0.f, 0.f}, ssq[3] = {0.f, 0.f, 0.f};
  const size_t nf = (size_t)N * NFEAT;

  float4 pf[4];
  // prologue prefetch for first tile
  {
    int gr = blockIdx.x * 64 + sr; if (gr >= N) gr = N - 1;
    const float4* s4 = (const float4*)(feat + (size_t)gr * NFEAT + so * 16);
#pragma unroll
    for (int q = 0; q < 4; q++) pf[q] = s4[q];
  }

  for (int tile = blockIdx.x; tile < ntiles; tile += gridDim.x) {
    const int row0 = tile * 64;
    __syncthreads();                  // prior epilogue LDS readers done
    // ---- convert prefetched regs, write LDS hi/lo planes
    {
      short hbuf[16], lbuf[16];
#pragma unroll
      for (int q = 0; q < 4; q++) {
        float xs[4] = {pf[q].x, pf[q].y, pf[q].z, pf[q].w};
#pragma unroll
        for (int cc = 0; cc < 4; cc++) {
          unsigned short h = f2bf(xs[cc]);
          hbuf[q * 4 + cc] = (short)h;
          lbuf[q * 4 + cc] = (short)f2bf(xs[cc] - bf2f(h));
        }
      }
      short* dh = &Ah[sr * LDA + so * 16];
      short* dl = &Al[sr * LDA + so * 16];
      *(short8*)(dh)     = *(short8*)(hbuf);
      *(short8*)(dh + 8) = *(short8*)(hbuf + 8);
      *(short8*)(dl)     = *(short8*)(lbuf);
      *(short8*)(dl + 8) = *(short8*)(lbuf + 8);
    }
    __syncthreads();

    // ---- issue next tile's prefetch (consumed next iteration)
    {
      int ntile = tile + gridDim.x;
      if (ntile < ntiles) {
        int gr = ntile * 64 + sr; if (gr >= N) gr = N - 1;
        const float4* s4 = (const float4*)(feat + (size_t)gr * NFEAT + so * 16);
#pragma unroll
        for (int q = 0; q < 4; q++) pf[q] = s4[q];
      }
    }

    // ---- MFMA main loop
    f32x4 acc[3][4];
#pragma unroll
    for (int m = 0; m < 3; m++)
#pragma unroll
      for (int rf = 0; rf < 4; rf++)
        acc[m][rf] = (f32x4){0.f, 0.f, 0.f, 0.f};

#pragma unroll
    for (int kf = 0; kf < 4; kf++) {
      short8 bh[3], bl[3];
#pragma unroll
      for (int m = 0; m < 3; m++) {
        int fb = ((m * 16 + kf * 4 + kg) << 10) + (colb << 3);
        bh[m] = *(const short8*)&Whi[fb];
        bl[m] = *(const short8*)&Wlo[fb];
      }
      short8 ah[4], al[4];
#pragma unroll
      for (int rf = 0; rf < 4; rf++) {
        int off = (rf * 16 + (lane & 15)) * LDA + kf * 32 + krow;
        ah[rf] = *(const short8*)&Ah[off];
        al[rf] = *(const short8*)&Al[off];
      }
#pragma unroll
      for (int m = 0; m < 3; m++) {
#pragma unroll
        for (int rf = 0; rf < 4; rf++) {
          acc[m][rf] = __builtin_amdgcn_mfma_f32_16x16x32_bf16(
              ah[rf], bh[m], acc[m][rf], 0, 0, 0);
          acc[m][rf] = __builtin_amdgcn_mfma_f32_16x16x32_bf16(
              al[rf], bh[m], acc[m][rf], 0, 0, 0);
          acc[m][rf] = __builtin_amdgcn_mfma_f32_16x16x32_bf16(
              ah[rf], bl[m], acc[m][rf], 0, 0, 0);
        }
      }
    }

    // ---- epilogue: + bias + residual(from LDS), store P, accumulate stats
#pragma unroll
    for (int rf = 0; rf < 4; rf++) {
      int lrb = rf * 16 + kg * 4;
#pragma unroll
      for (int g = 0; g < 4; g++) {
        int lr = lrb + g;
        int gr = row0 + lr;
        bool ok = gr < N;
        float res = bf2f((unsigned short)Ah[lr * LDA + colb]) +
                    bf2f((unsigned short)Al[lr * LDA + colb]);
#pragma unroll
        for (int m = 0; m < 3; m++) {
          float v = acc[m][rf][g] + bias[m] + res;
          if (ok) {
            Pout[(size_t)m * nf + (size_t)gr * NFEAT + colb] = v;
            ssum[m] += v;
            ssq[m]  += v * v;
          }
        }
      }
    }
  }

  // ---- one atomic set per block
#pragma unroll
  for (int m = 0; m < 3; m++) {
    float s = ssum[m], q = ssq[m];
    s += __shfl_xor(s, 16); s += __shfl_xor(s, 32);
    q += __shfl_xor(q, 16); q += __shfl_xor(q, 32);
    if (kg == 0) {
      unsafeAtomicAdd(&stats[m * 256 + colb], s);
      unsafeAtomicAdd(&stats[m * 256 + 128 + colb], q);
    }
  }
}

// ---------------------------------------------------------------------------
// K2a: fold back-half into MT (4 x 128 x 3) + cb.  grid=6.
//   logits = S@M1 + I@M3 + R@M4 + NB@M2 + cb
// MT layout: MT[cl*512 + part*128 + k], part: 0=S 1=I 2=R 3=NB.
// ---------------------------------------------------------------------------
__global__ void k2a_fold(
    const float* __restrict__ WtoI, const float* __restrict__ btoI,
    const float* __restrict__ WtoR, const float* __restrict__ btoR,
    const float* __restrict__ Wout, const float* __restrict__ bout,
    float* __restrict__ MT,   // 3*512
    float* __restrict__ cb)   // 4
{
  const int tid = threadIdx.x;
  int t = blockIdx.x * 256 + tid;     // 0..1535
  int cl = t / 512;
  int idx = t - cl * 512;
  int part = idx >> 7, k = idx & 127;
  float val;
  if (part == 0) {            // S: Wo1 + WtoI_top @ (Wo2-Wo1)
    float s = Wout[k * 3 + cl];
    for (int f = 0; f < 128; f++)
      s = fmaf(WtoI[k * 128 + f],
               Wout[(128 + f) * 3 + cl] - Wout[f * 3 + cl], s);
    val = s;
  } else if (part == 1) {     // I: Wo2 + WtoR @ (Wo3-Wo2)
    float s = Wout[(128 + k) * 3 + cl];
    for (int f = 0; f < 128; f++)
      s = fmaf(WtoR[k * 128 + f],
               Wout[(256 + f) * 3 + cl] - Wout[(128 + f) * 3 + cl], s);
    val = s;
  } else if (part == 2) {     // R: Wo3
    val = Wout[(256 + k) * 3 + cl];
  } else {                    // NB: WtoI_bot @ (Wo2-Wo1)
    float s = 0.f;
    for (int f = 0; f < 128; f++)
      s = fmaf(WtoI[(128 + k) * 128 + f],
               Wout[(128 + f) * 3 + cl] - Wout[f * 3 + cl], s);
    val = s;
  }
  MT[cl * 512 + idx] = val;

  if (blockIdx.x == 0 && tid < 3) {
    float s = bout[tid];
    for (int f = 0; f < 128; f++) {
      s = fmaf(btoI[f], Wout[(128 + f) * 3 + tid] - Wout[f * 3 + tid], s);
      s = fmaf(btoR[f], Wout[(256 + f) * 3 + tid] - Wout[(128 + f) * 3 + tid], s);
    }
    cb[tid] = s;
  }
}

// ---------------------------------------------------------------------------
// K2b: BN scale/shift from stats (1 block).
// ---------------------------------------------------------------------------
__global__ void k2b_bn(
    const float* __restrict__ stats,
    const float* __restrict__ gamma, const float* __restrict__ beta,
    float* __restrict__ bn,   // 6*128: [w]{a[128], b[128]}
    int N)
{
  const int tid = threadIdx.x;
  const float invN = 1.0f / (float)N;
  for (int t = tid; t < 384; t += 256) {
    int w = t >> 7, c = t & 127;
    float sm = stats[w * 256 + c];
    float sq = stats[w * 256 + 128 + c];
    float m = sm * invN;
    float v = sq * invN - m * m;
    float rinv = rsqrtf(v + EPSBN);
    float a = gamma[c] * rinv;
    bn[w * 256 + c] = a;
    bn[w * 256 + 128 + c] = beta[c] - m * a;
  }
}

// ---------------------------------------------------------------------------
// KQ: per-node projection  q[r] = relu(bn_i(P_i[r])) @ M2   (32 lanes/row).
// ---------------------------------------------------------------------------
__global__ __launch_bounds__(256) void kq_proj(
    const float* __restrict__ Pi,
    const float* __restrict__ bn, const float* __restrict__ MT,
    float* __restrict__ q, int N)
{
  int r = blockIdx.x * 8 + (threadIdx.x >> 5);
  if (r >= N) return;
  const int c = (threadIdx.x & 31) * 4;

  float4 x = *(const float4*)&Pi[(size_t)r * NFEAT + c];
  float4 a = *(const float4*)&bn[256 + c];
  float4 b = *(const float4*)&bn[256 + 128 + c];
  float m0 = fmaxf(fmaf(a.x, x.x, b.x), 0.f);
  float m1 = fmaxf(fmaf(a.y, x.y, b.y), 0.f);
  float m2 = fmaxf(fmaf(a.z, x.z, b.z), 0.f);
  float m3 = fmaxf(fmaf(a.w, x.w, b.w), 0.f);

  float l[3];
#pragma unroll
  for (int cl = 0; cl < 3; cl++) {
    float4 m = *(const float4*)&MT[cl * 512 + 384 + c];
    l[cl] = m0 * m.x + m1 * m.y + m2 * m.z + m3 * m.w;
  }
#pragma unroll
  for (int off = 1; off < 32; off <<= 1) {
    l[0] += __shfl_xor(l[0], off);
    l[1] += __shfl_xor(l[1], off);
    l[2] += __shfl_xor(l[2], off);
  }
  if ((threadIdx.x & 31) == 0)
    *(float4*)&q[(size_t)r * 4] = make_float4(l[0], l[1], l[2], 0.f);
}

// ---------------------------------------------------------------------------
// K_edge: 64 lanes = 21 edges x 3 components (lane 63 idle).  Each lane does
// ONE atomic; an edge's 3 lanes hit 3 consecutive floats (same 64B line ->
// per-instruction merge).  Replica (waveID&7) spreads same-line contention.
// ---------------------------------------------------------------------------
__global__ __launch_bounds__(256) void k_edge(
    const int* __restrict__ eidx, const float* __restrict__ ew,
    const float* __restrict__ q, float* __restrict__ logit3R,
    int E, int N4)
{
  const int wid  = (blockIdx.x * 256 + threadIdx.x) >> 6;  // global wave id
  const int lane = threadIdx.x & 63;
  const int el   = lane / 3;          // edge-in-wave 0..21
  const int comp = lane - el * 3;     // 0..2
  if (el >= 21) return;               // lane 63 idle
  const int e = wid * 21 + el;
  if (e >= E) return;

  int src = eidx[e];
  int dst = eidx[E + e];
  float w = ew[e];
  float qv = q[(size_t)src * 4 + comp];
  int rep = wid & (NREP - 1);
  unsafeAtomicAdd(&logit3R[(size_t)rep * N4 + (size_t)dst * 4 + comp], qv * w);
}

// ---------------------------------------------------------------------------
// K4: per-row fused BN+ReLU, S/I/R dots with folded MT + neighbor logits
// (summed over NREP replicas by lanes p=12..15), softmax.  16 lanes/row.
// ---------------------------------------------------------------------------
__global__ __launch_bounds__(256) void k4_final(
    const float* __restrict__ P,   // 3 consecutive N x 128
    const float* __restrict__ logit3R,
    const float* __restrict__ bn,
    const float* __restrict__ MT,
    const float* __restrict__ cb,
    float* __restrict__ out, int N, int N4)
{
  __shared__ float MTs[1536];
  __shared__ float bns[768];
  const int tid = threadIdx.x;
  for (int i = tid; i < 1536; i += 256) MTs[i] = MT[i];
  for (int i = tid; i < 768; i += 256) bns[i] = bn[i];
  __syncthreads();

  const int row0 = blockIdx.x * 16 + (tid >> 4);
  const int row  = (row0 < N) ? row0 : (N - 1);
  const int p   = tid & 15;
  const int mp  = p >> 2;       // 0=S 1=I 2=R 3=neighbor-logit replicas
  const int seg = p & 3;

  float pa0 = 0.f, pa1 = 0.f, pa2 = 0.f;
  if (mp < 3) {
    const float* xsrc = P + ((size_t)mp * N + row) * NFEAT + seg * 32;
#pragma unroll
    for (int i = 0; i < 8; i++) {
      float4 x = *(const float4*)&xsrc[i * 4];
      int c = seg * 32 + i * 4;
      float4 a = *(float4*)&bns[mp * 256 + c];
      float4 b = *(float4*)&bns[mp * 256 + 128 + c];
      x.x = fmaxf(fmaf(a.x, x.x, b.x), 0.f);
      x.y = fmaxf(fmaf(a.y, x.y, b.y), 0.f);
      x.z = fmaxf(fmaf(a.z, x.z, b.z), 0.f);
      x.w = fmaxf(fmaf(a.w, x.w, b.w), 0.f);
      int mo = mp * 128 + c;
      {
        float4 m = *(float4*)&MTs[0 * 512 + mo];
        pa0 += x.x * m.x + x.y * m.y + x.z * m.z + x.w * m.w;
      }
      {
        float4 m = *(float4*)&MTs[1 * 512 + mo];
        pa1 += x.x * m.x + x.y * m.y + x.z * m.z + x.w * m.w;
      }
      {
        float4 m = *(float4*)&MTs[2 * 512 + mo];
        pa2 += x.x * m.x + x.y * m.y + x.z * m.z + x.w * m.w;
      }
    }
  } else {
    // each of the 4 lanes sums 2 replicas; shfl-reduce folds them
    float4 La = *(const float4*)&logit3R[(size_t)seg * N4 + (size_t)row * 4];
    float4 Lb = *(const float4*)&logit3R[(size_t)(seg + 4) * N4 + (size_t)row * 4];
    pa0 = La.x + Lb.x; pa1 = La.y + Lb.y; pa2 = La.z + Lb.z;
  }

#pragma unroll
  for (int off = 1; off < 16; off <<= 1) {
    pa0 += __shfl_xor(pa0, off);
    pa1 += __shfl_xor(pa1, off);
    pa2 += __shfl_xor(pa2, off);
  }
  if (p == 0 && row0 < N) {
    float l0 = pa0 + cb[0], l1 = pa1 + cb[1], l2 = pa2 + cb[2];
    float mx = fmaxf(l0, fmaxf(l1, l2));
    float e0 = expf(l0 - mx), e1 = expf(l1 - mx), e2 = expf(l2 - mx);
    float inv = 1.f / (e0 + e1 + e2);
    out[(size_t)row0 * 3 + 0] = e0 * inv;
    out[(size_t)row0 * 3 + 1] = e1 * inv;
    out[(size_t)row0 * 3 + 2] = e2 * inv;
  }
}

// ---------------------------------------------------------------------------
extern "C" void kernel_launch(void* const* d_in, const int* in_sizes, int n_in,
                              void* d_out, int out_size, void* d_ws, size_t ws_size,
                              hipStream_t stream)
{
  const float* feat  = (const float*)d_in[0];
  const int*   eidx  = (const int*)  d_in[1];
  const float* ew    = (const float*)d_in[2];
  const float* Ws    = (const float*)d_in[3];
  const float* bs    = (const float*)d_in[4];
  const float* Wi    = (const float*)d_in[5];
  const float* bi    = (const float*)d_in[6];
  const float* Wr    = (const float*)d_in[7];
  const float* br    = (const float*)d_in[8];
  const float* gamma = (const float*)d_in[9];
  const float* beta  = (const float*)d_in[10];
  const float* WtoI  = (const float*)d_in[11];
  const float* btoI  = (const float*)d_in[12];
  const float* WtoR  = (const float*)d_in[13];
  const float* btoR  = (const float*)d_in[14];
  const float* Wout  = (const float*)d_in[15];
  const float* bout  = (const float*)d_in[16];

  const int N = in_sizes[0] / NFEAT;
  const int E = in_sizes[2];
  const int N4 = 4 * N;
  float* out = (float*)d_out;

  const size_t nf = (size_t)N * NFEAT;
  float* P       = (float*)d_ws;               // 3*nf
  float* logit3R = P + 3 * nf;                 // NREP*4*N
  float* q       = logit3R + (size_t)NREP * N4; // 4*N
  float* stats   = q + 4 * (size_t)N;          // 768
  float* bn      = stats + 768;                // 768
  float* MT      = bn + 768;                   // 1536
  float* cb      = MT + 1536;                  // 4
  short* Whi     = (short*)(cb + 4);           // 49152
  short* Wlo     = Whi + 49152;                // 49152

  hipMemsetAsync(stats, 0, 768 * sizeof(float), stream);
  hipMemsetAsync(logit3R, 0, (size_t)NREP * N4 * sizeof(float), stream);

  const int nt = (N + 63) / 64;           // 1563
  const int g1 = (nt + 2) / 3;            // 521: 3 tiles per block

  k0_wsplit<<<24, 256, 0, stream>>>(Ws, Wi, Wr, Whi, Wlo);
  k2a_fold<<<6, 256, 0, stream>>>(WtoI, btoI, WtoR, btoR, Wout, bout, MT, cb);
  k1_gemm<<<g1, 512, 0, stream>>>(feat, Whi, Wlo, bs, bi, br, P, stats, N, nt);
  k2b_bn<<<1, 256, 0, stream>>>(stats, gamma, beta, bn, N);

  kq_proj<<<(N + 7) / 8, 256, 0, stream>>>(P + nf, bn, MT, q, N);
  const int nwaves = (E + 20) / 21;
  k_edge<<<(nwaves + 3) / 4, 256, 0, stream>>>(eidx, ew, q, logit3R, E, N4);
  k4_final<<<(N + 15) / 16, 256, 0, stream>>>(P, logit3R, bn, MT, cb, out, N, N4);
}